// Round 4
// baseline (1601.526 us; speedup 1.0000x reference)
//
#include <hip/hip_runtime.h>
#include <cstdint>

typedef _Float16 half8 __attribute__((ext_vector_type(8)));
typedef float f32x4 __attribute__((ext_vector_type(4)));

#define T_STEPS 16
#define NB 8
#define CCH 64
#define HH 64
#define WW 64
#define HW 4096
#define NCHW (NB * CCH * HW)          // 2097152
#define XTSTR (NB * 2 * CCH * HW)

#define CI_PAD 40                      // halves per (r,c) cell: 80B stride, 16B aligned
#define IN_LDS (4 * 66 * CI_PAD)

__device__ __forceinline__ unsigned short h_bits(_Float16 h) {
    union { _Float16 h; unsigned short u; } v; v.h = h; return v.u;
}
// fp32 -> f16 hi + f16 (residual*2048); recombine hi + lo/2048 ~ fp32-exact
__device__ __forceinline__ void split2(float x, unsigned short& hb, unsigned short& lb) {
    _Float16 hi = (_Float16)x;
    _Float16 lo = (_Float16)((x - (float)hi) * 2048.0f);
    hb = h_bits(hi); lb = h_bits(lo);
}
__device__ __forceinline__ uint32_t pack2(float x) {
    unsigned short h, l; split2(x, h, l); return ((uint32_t)h << 16) | l;
}

// ---------------------------------------------------------------------------
// One-time weight prepack: wpack[g][tap][chunk][ch][co32][ci32] = hi<<16|lo
// ---------------------------------------------------------------------------
__global__ __launch_bounds__(256) void prep_w(const float* __restrict__ w_rz,
                                              const float* __restrict__ w_f,
                                              uint32_t* __restrict__ wpack) {
    int i = blockIdx.x * 256 + threadIdx.x;
    if (i >= 2 * 9 * 2 * 2 * 32 * 32) return;
    int ci = i & 31, co = (i >> 5) & 31, ch = (i >> 10) & 1, chunk = (i >> 11) & 1;
    int gt = i >> 12; int tap = gt % 9; int g = gt / 9;
    const float* w = g ? w_f : w_rz;
    float v = w[(size_t)((ch * 32 + co) * CCH + (chunk * 32 + ci)) * 9 + tap];
    wpack[i] = pack2(v);
}

// ---------------------------------------------------------------------------
// Stage one ci-chunk (32) of packed input into split LDS.
// ---------------------------------------------------------------------------
__device__ __forceinline__ void stage_pk(const uint32_t* __restrict__ pk, int n, int y0,
                                         int chunk, _Float16* __restrict__ s_hi,
                                         _Float16* __restrict__ s_lo, int tid) {
    #pragma unroll
    for (int it = 0; it < 5; ++it) {
        int i = tid + it * 256;
        if (i >= 1056) break;                 // 4 rows x 66 cols x 4 granules
        int gg = i & 3; int tmp = i >> 2; int c = tmp % 66; int r = tmp / 66;
        int gr = y0 - 1 + r, gc = c - 1;
        uint4 ua = make_uint4(0,0,0,0), ub = make_uint4(0,0,0,0);
        if ((unsigned)gr < 64u && (unsigned)gc < 64u) {
            const uint32_t* p = pk + ((((size_t)n * 64 + gr) * 64 + gc) * 64
                                      + chunk * 32 + gg * 8);
            ua = *(const uint4*)p; ub = *(const uint4*)(p + 4);
        }
        uint32_t hw0 = (ua.x >> 16) | (ua.y & 0xFFFF0000u), lw0 = (ua.x & 0xFFFFu) | (ua.y << 16);
        uint32_t hw1 = (ua.z >> 16) | (ua.w & 0xFFFF0000u), lw1 = (ua.z & 0xFFFFu) | (ua.w << 16);
        uint32_t hw2 = (ub.x >> 16) | (ub.y & 0xFFFF0000u), lw2 = (ub.x & 0xFFFFu) | (ub.y << 16);
        uint32_t hw3 = (ub.z >> 16) | (ub.w & 0xFFFF0000u), lw3 = (ub.z & 0xFFFFu) | (ub.w << 16);
        int off = (r * 66 + c) * CI_PAD + gg * 8;
        *(uint4*)&s_hi[off] = make_uint4(hw0, hw1, hw2, hw3);
        *(uint4*)&s_lo[off] = make_uint4(lw0, lw1, lw2, lw3);
    }
}

// ---------------------------------------------------------------------------
// Weight group (3 taps, one ci-chunk, one co-half): coalesced uint4/thread.
// ---------------------------------------------------------------------------
__device__ __forceinline__ void wload(const uint32_t* __restrict__ wp, int gi, int ch,
                                      int tid, uint4* u) {
    int chunk = gi / 3, ty = gi - chunk * 3;
    #pragma unroll
    for (int tx = 0; tx < 3; ++tx) {
        const uint32_t* p = wp + (size_t)(((ty * 3 + tx) * 2 + chunk) * 2 + ch) * 1024
                          + tid * 4;
        u[tx] = *(const uint4*)p;
    }
}

__device__ __forceinline__ void wwrite(const uint4* u, _Float16 (*sw)[2][1024], int tid) {
    int co = tid >> 3, j = tid & 7;
    int pos = ((j >> 1) ^ (co ^ (co >> 2))) & 3;       // granule swizzle
    int off = co * 32 + pos * 8 + (j & 1) * 4;
    #pragma unroll
    for (int tx = 0; tx < 3; ++tx) {
        uint4 q = u[tx];
        uint32_t hw0 = (q.x >> 16) | (q.y & 0xFFFF0000u), lw0 = (q.x & 0xFFFFu) | (q.y << 16);
        uint32_t hw1 = (q.z >> 16) | (q.w & 0xFFFF0000u), lw1 = (q.z & 0xFFFFu) | (q.w << 16);
        *(uint2*)&sw[tx][0][off] = make_uint2(hw0, hw1);
        *(uint2*)&sw[tx][1][off] = make_uint2(lw0, lw1);
    }
}

// ---------------------------------------------------------------------------
// Conv core: 32co x 128sp tile, split-f16 MFMA (verified round 3).
// ---------------------------------------------------------------------------
__device__ __forceinline__ void conv_core(const uint32_t* __restrict__ in_pk,
    const uint32_t* __restrict__ wp, int n, int y0, int ch, int tid,
    f32x4 acc1[2][2], f32x4 acc2[2][2],
    _Float16* s_in_h, _Float16* s_in_l, _Float16 (*s_w)[3][2][1024]) {

    int wv = tid >> 6, l = tid & 63, lg = l >> 4, ln = l & 15;
    int aoff = ln * 32 + ((lg ^ ln ^ (ln >> 2)) & 3) * 8;

    uint4 wreg[3];
    stage_pk(in_pk, n, y0, 0, s_in_h, s_in_l, tid);
    wload(wp, 0, ch, tid, wreg);
    wwrite(wreg, s_w[0], tid);
    wload(wp, 1, ch, tid, wreg);
    __syncthreads();

    int db = 0;
    for (int gi = 0; gi < 6; ++gi) {
        int ty = gi % 3;
        if (gi < 5) {
            wwrite(wreg, s_w[db ^ 1], tid);
            if (gi + 2 < 6) wload(wp, gi + 2, ch, tid, wreg);
        }
        #pragma unroll
        for (int tx = 0; tx < 3; ++tx) {
            half8 afh[2], afl[2];
            #pragma unroll
            for (int ct = 0; ct < 2; ++ct) {
                afh[ct] = *(const half8*)&s_w[db][tx][0][ct * 512 + aoff];
                afl[ct] = *(const half8*)&s_w[db][tx][1][ct * 512 + aoff];
            }
            half8 bfh[2], bfl[2];
            #pragma unroll
            for (int st = 0; st < 2; ++st) {
                int sp = wv * 32 + st * 16 + ln;
                int boff = (((sp >> 6) + ty) * 66 + (sp & 63) + tx) * CI_PAD + lg * 8;
                bfh[st] = *(const half8*)&s_in_h[boff];
                bfl[st] = *(const half8*)&s_in_l[boff];
            }
            #pragma unroll
            for (int ct = 0; ct < 2; ++ct)
                #pragma unroll
                for (int st = 0; st < 2; ++st) {
                    acc1[ct][st] = __builtin_amdgcn_mfma_f32_16x16x32_f16(afh[ct], bfh[st], acc1[ct][st], 0, 0, 0);
                    acc2[ct][st] = __builtin_amdgcn_mfma_f32_16x16x32_f16(afh[ct], bfl[st], acc2[ct][st], 0, 0, 0);
                    acc2[ct][st] = __builtin_amdgcn_mfma_f32_16x16x32_f16(afl[ct], bfh[st], acc2[ct][st], 0, 0, 0);
                }
        }
        if (gi == 2) {
            __syncthreads();
            stage_pk(in_pk, n, y0, 1, s_in_h, s_in_l, tid);
        }
        __syncthreads();
        db ^= 1;
    }
}

// ---------------------------------------------------------------------------
// Neighbor-flag sync (agent scope; halo = 3 strips x 2 co-halves)
// ---------------------------------------------------------------------------
__device__ __forceinline__ void wait_nbrs(const uint32_t* __restrict__ flags,
                                          int n, int strip, int tid) {
    if (tid < 6) {
        int s2 = strip + (tid >> 1) - 1;
        int ch2 = tid & 1;
        if ((unsigned)s2 < 32u) {
            const uint32_t* f = flags + ((n << 6) | (s2 << 1) | ch2);
            while (__hip_atomic_load(f, __ATOMIC_RELAXED, __HIP_MEMORY_SCOPE_AGENT) == 0u)
                __builtin_amdgcn_s_sleep(2);
            __builtin_amdgcn_fence(__ATOMIC_ACQUIRE, "agent");
        }
    }
    __syncthreads();
}

__device__ __forceinline__ void post_flag(uint32_t* __restrict__ f, int tid) {
    __syncthreads();                 // drains vmcnt: all block stores in L2
    if (tid == 0) {
        __builtin_amdgcn_fence(__ATOMIC_RELEASE, "agent");   // wb L2
        __hip_atomic_store(f, 1u, __ATOMIC_RELAXED, __HIP_MEMORY_SCOPE_AGENT);
    }
}

// ---------------------------------------------------------------------------
// Persistent scan kernel: 512 blocks (2/CU), block owns (n, 2-row strip, ch).
// h, f, prev_y in registers across all T steps.
// ---------------------------------------------------------------------------
__global__ __launch_bounds__(256, 2) void kMain(
    const uint32_t* __restrict__ wpack, const float* __restrict__ b_rz,
    const float* __restrict__ b_f, const float* __restrict__ xt,
    const float* __restrict__ thr_rp, uint32_t* __restrict__ a_pk,
    uint32_t* __restrict__ y_pk, uint32_t* __restrict__ flagA,
    uint32_t* __restrict__ flagY, float* __restrict__ out) {

    __shared__ __align__(16) _Float16 s_in_h[IN_LDS];
    __shared__ __align__(16) _Float16 s_in_l[IN_LDS];
    __shared__ __align__(16) _Float16 s_w[2][3][2][1024];

    int tid = threadIdx.x, wv = tid >> 6, l = tid & 63, lg = l >> 4, ln = l & 15;
    // XCD swizzle: one batch element per XCD -> halo/flag traffic intra-XCD
    int bid = ((blockIdx.x & 7) << 6) | (blockIdx.x >> 3);
    int n = bid >> 6, strip = (bid >> 1) & 31, ch = bid & 1, y0 = strip * 2;

    const uint32_t* wpkA = wpack;             // w_rz
    const uint32_t* wpkB = wpack + 9 * 4096;  // w_f

    // per-thread output coords (one (row,col) pair per st)
    int rr[2], cc[2];
    float thrv[2];
    #pragma unroll
    for (int st = 0; st < 2; ++st) {
        int sp = wv * 32 + st * 16 + ln;
        rr[st] = y0 + (sp >> 6); cc[st] = sp & 63;
        thrv[st] = 1.0f / (1.0f + expf(-thr_rp[rr[st] * WW + cc[st]]));
    }
    float brz[2][4], bfv[2][4];
    #pragma unroll
    for (int ct = 0; ct < 2; ++ct)
        #pragma unroll
        for (int r = 0; r < 4; ++r) {
            int co = ch * 32 + ct * 16 + lg * 4 + r;
            brz[ct][r] = b_rz[co]; bfv[ct][r] = b_f[co];
        }

    float h[2][2][4] = {}, fg[2][2][4] = {}, py[2][2][4] = {};

    float* ys0 = out;
    float* ev0 = out + (size_t)T_STEPS * NCHW;
    float* nd0 = ev0 + (size_t)T_STEPS * NCHW;

    #pragma unroll 1
    for (int t = 0; t < T_STEPS; ++t) {
        const float* xt_t = xt + (size_t)t * XTSTR;

        // ================= phase A =================
        f32x4 acc1[2][2] = {}, acc2[2][2] = {};
        if (t > 0) {
            wait_nbrs(flagY + (size_t)(t - 1) * 512, n, strip, tid);
            conv_core(y_pk, wpkA, n, y0, ch, tid, acc1, acc2, s_in_h, s_in_l, s_w);
        }
        #pragma unroll
        for (int ct = 0; ct < 2; ++ct)
            #pragma unroll
            for (int st = 0; st < 2; ++st) {
                int row = rr[st], col = cc[st];
                uint32_t pk[4];
                #pragma unroll
                for (int r = 0; r < 4; ++r) {
                    int co = ch * 32 + ct * 16 + lg * 4 + r;
                    float conv = (t > 0)
                        ? (acc1[ct][st][r] + acc2[ct][st][r] * (1.0f / 2048.0f)) : 0.0f;
                    float xi = xt_t[(((size_t)n * 128 + co) * 64 + row) * 64 + col];
                    float s = conv + brz[ct][r] + xi;
                    float fv = 1.0f / (1.0f + expf(-s));
                    fg[ct][st][r] = fv;
                    pk[r] = pack2(py[ct][st][r] * fv);
                }
                *(uint4*)&a_pk[(((size_t)n * 64 + row) * 64 + col) * 64
                               + ch * 32 + ct * 16 + lg * 4] =
                    make_uint4(pk[0], pk[1], pk[2], pk[3]);
            }
        post_flag(flagA + (size_t)t * 512 + bid, tid);

        // ================= phase B =================
        wait_nbrs(flagA + (size_t)t * 512, n, strip, tid);
        f32x4 bc1[2][2] = {}, bc2[2][2] = {};
        conv_core(a_pk, wpkB, n, y0, ch, tid, bc1, bc2, s_in_h, s_in_l, s_w);

        float* ys_t = ys0 + (size_t)t * NCHW;
        float* ev_t = ev0 + (size_t)t * NCHW;
        float* nd_t = nd0 + (size_t)t * NCHW;
        #pragma unroll
        for (int ct = 0; ct < 2; ++ct)
            #pragma unroll
            for (int st = 0; st < 2; ++st) {
                int row = rr[st], col = cc[st];
                float thr = thrv[st];
                uint32_t pk[4];
                #pragma unroll
                for (int r = 0; r < 4; ++r) {
                    int co = ch * 32 + ct * 16 + lg * 4 + r;
                    float conv = bc1[ct][st][r] + bc2[ct][st][r] * (1.0f / 2048.0f);
                    float xi = xt_t[(((size_t)n * 128 + 64 + co) * 64 + row) * 64 + col];
                    float s  = conv + bfv[ct][r] + xi;
                    float e2 = expf(2.0f * s);
                    float g  = 1.0f - 2.0f / (e2 + 1.0f);       // tanh(s)
                    float fv = fg[ct][st][r];
                    float hn = (1.0f - fv) * h[ct][st][r] + fv * g;
                    float d  = hn - thr;
                    bool  e  = d > 0.0f;
                    float y  = e ? hn : 0.0f;
                    size_t idx = (((size_t)n * 64 + co) * 64 + row) * 64 + col;
                    ys_t[idx] = y;
                    ev_t[idx] = e ? 1.0f : 0.0f;
                    nd_t[idx] = (d < 0.0f) ? (thr - hn) : 0.0f;
                    h[ct][st][r]  = e ? d : hn;                 // h - event*thr
                    py[ct][st][r] = y;
                    pk[r] = pack2(y);
                }
                *(uint4*)&y_pk[(((size_t)n * 64 + row) * 64 + col) * 64
                               + ch * 32 + ct * 16 + lg * 4] =
                    make_uint4(pk[0], pk[1], pk[2], pk[3]);
            }
        post_flag(flagY + (size_t)t * 512 + bid, tid);
    }
}

// ---------------------------------------------------------------------------
extern "C" void kernel_launch(void* const* d_in, const int* in_sizes, int n_in,
                              void* d_out, int out_size, void* d_ws, size_t ws_size,
                              hipStream_t stream) {
    (void)in_sizes; (void)n_in; (void)out_size; (void)ws_size;

    const float* xt     = (const float*)d_in[0];
    const float* w_rz   = (const float*)d_in[1];
    const float* b_rz   = (const float*)d_in[2];
    const float* w_f    = (const float*)d_in[3];
    const float* b_f    = (const float*)d_in[4];
    const float* thr_rp = (const float*)d_in[5];

    float* out = (float*)d_out;
    uint32_t* a_pk   = (uint32_t*)d_ws;                   // NCHW u32 (8 MB)
    uint32_t* y_pk   = a_pk + NCHW;                       // NCHW u32 (8 MB)
    uint32_t* wpack  = y_pk + NCHW;                       // 73728 u32
    uint32_t* flags  = wpack + 73728;                     // 2*16*512 u32
    uint32_t* flagA  = flags;
    uint32_t* flagY  = flags + 16 * 512;

    hipMemsetAsync(flags, 0, 2 * 16 * 512 * sizeof(uint32_t), stream);
    prep_w<<<288, 256, 0, stream>>>(w_rz, w_f, wpack);
    kMain<<<512, 256, 0, stream>>>(wpack, b_rz, b_f, xt, thr_rp,
                                   a_pk, y_pk, flagA, flagY, out);
}

// Round 5
// 1173.494 us; speedup vs baseline: 1.3647x; 1.3647x over previous
//
#include <hip/hip_runtime.h>
#include <cstdint>

typedef _Float16 half4v __attribute__((ext_vector_type(4)));
typedef float f32x4 __attribute__((ext_vector_type(4)));

#define T_STEPS 16
#define NB 8
#define CCH 64
#define HH 64
#define WW 64
#define NCHW (NB * CCH * HH * WW)     // 2097152
#define XTSTR (NB * 2 * CCH * HH * WW)

__device__ __forceinline__ unsigned short h_bits(_Float16 h) {
    union { _Float16 h; unsigned short u; } v; v.h = h; return v.u;
}
__device__ __forceinline__ float h2f(uint32_t b) {
    union { _Float16 h; unsigned short u; } v; v.u = (unsigned short)b; return (float)v.h;
}
// fp32 -> f16 hi + f16 (residual*2048); recombine hi + lo/2048 ~ fp32-exact
__device__ __forceinline__ void split2(float x, unsigned short& hb, unsigned short& lb) {
    _Float16 hi = (_Float16)x;
    _Float16 lo = (_Float16)((x - (float)hi) * 2048.0f);
    hb = h_bits(hi); lb = h_bits(lo);
}
__device__ __forceinline__ uint32_t pack2(float x) {
    unsigned short h, l; split2(x, h, l); return ((uint32_t)h << 16) | l;
}

// ---------------------------------------------------------------------------
// Weight prepack: wpack[g][tap 9][chunk 4][co 64][ci 16] = hi<<16|lo
// ---------------------------------------------------------------------------
__global__ __launch_bounds__(256) void prep_w(const float* __restrict__ w_rz,
                                              const float* __restrict__ w_f,
                                              uint32_t* __restrict__ wpack) {
    int i = blockIdx.x * 256 + threadIdx.x;
    if (i >= 2 * 9 * 4 * 64 * 16) return;
    int ci = i & 15, co = (i >> 4) & 63, chunk = (i >> 10) & 3;
    int rest = i >> 12;                    // 0..17
    int tap = rest % 9, g = rest / 9;
    const float* w = g ? w_f : w_rz;
    float v = w[(size_t)(co * 64 + chunk * 16 + ci) * 9 + tap];
    wpack[i] = pack2(v);
}

// ---------------------------------------------------------------------------
// Stage one 16-ci chunk of packed y into split LDS: cells [6 rows][66 cols],
// 20-half stride (40B, 8B aligned), quad-swizzle pos = q ^ (c&3).
// ---------------------------------------------------------------------------
__device__ __forceinline__ void stage_y(const uint32_t* __restrict__ ypk, int n, int y0,
                                        int chunk, _Float16* __restrict__ sh,
                                        _Float16* __restrict__ sl, int tid) {
    #pragma unroll
    for (int it = 0; it < 4; ++it) {
        int i = tid + it * 512;
        if (i >= 1584) break;              // 396 cells x 4 quads
        int q = i & 3, cell = i >> 2;
        int r = cell / 66, c = cell - r * 66;
        int gr = y0 - 2 + r, gc = c - 1;
        uint4 u = make_uint4(0, 0, 0, 0);
        if ((unsigned)gr < 64u && (unsigned)gc < 64u)
            u = *(const uint4*)(ypk + ((((size_t)n * 64 + gr) * 64 + gc) * 64
                                       + chunk * 16 + q * 4));
        uint32_t hw0 = (u.x >> 16) | (u.y & 0xFFFF0000u), lw0 = (u.x & 0xFFFFu) | (u.y << 16);
        uint32_t hw1 = (u.z >> 16) | (u.w & 0xFFFF0000u), lw1 = (u.z & 0xFFFFu) | (u.w << 16);
        int off = cell * 20 + (q ^ (c & 3)) * 4;
        *(uint2*)&sh[off] = make_uint2(hw0, hw1);
        *(uint2*)&sl[off] = make_uint2(lw0, lw1);
    }
}

// ---------------------------------------------------------------------------
// Weight group load/write: group fg = chunk*3 + ty (3 taps each).
// s_w cell = co (20-half stride), quad-swizzle pos = q ^ (co&3).
// ---------------------------------------------------------------------------
__device__ __forceinline__ void wload16(const uint32_t* __restrict__ wp, int fg,
                                        int tid, uint2* u) {
    int chunk = fg / 3, ty = fg - chunk * 3;
    int co = tid >> 3, ci0 = (tid & 7) * 2;
    #pragma unroll
    for (int tx = 0; tx < 3; ++tx) {
        int tap = ty * 3 + tx;
        u[tx] = *(const uint2*)(wp + (((tap * 4 + chunk) * 64 + co) * 16 + ci0));
    }
}
__device__ __forceinline__ void wwrite16(const uint2* u, _Float16 (*sw)[2][1280], int tid) {
    int co = tid >> 3, ci0 = (tid & 7) * 2;
    int off = co * 20 + ((ci0 >> 2) ^ (co & 3)) * 4 + (ci0 & 3);
    #pragma unroll
    for (int tx = 0; tx < 3; ++tx) {
        uint32_t hw = (u[tx].x >> 16) | (u[tx].y & 0xFFFF0000u);
        uint32_t lw = (u[tx].x & 0xFFFFu) | (u[tx].y << 16);
        *(uint32_t*)&sw[tx][0][off] = hw;
        *(uint32_t*)&sw[tx][1][off] = lw;
    }
}

// ---------------------------------------------------------------------------
// Fused per-timestep kernel: 256 blocks x 512 threads, 1 block/CU.
// Block = (n, 2-row strip). Phase A: f/a over 4 rows (halo-redundant) x 64co,
// a -> LDS. Phase B: conv(a) from LDS, GRU/spike update, outputs.
// ---------------------------------------------------------------------------
template<bool ZERO>
__global__ __launch_bounds__(512) void kStep(
    const uint32_t* __restrict__ wpkA, const uint32_t* __restrict__ wpkB,
    const float* __restrict__ b_rz, const float* __restrict__ b_f,
    const float* __restrict__ xt_t, const float* __restrict__ thr_rp,
    const uint32_t* __restrict__ ypk_prev, uint32_t* __restrict__ ypk_out,
    float* __restrict__ h_buf, float* __restrict__ ys,
    float* __restrict__ ev, float* __restrict__ nd) {

    __shared__ __align__(16) _Float16 s_sth[7920], s_stl[7920];   // y staging (6x66, 16ci)
    __shared__ __align__(16) _Float16 s_ah[16896], s_al[16896];   // a: 4x66x64ci
    __shared__ __align__(16) _Float16 s_w[2][3][2][1280];         // weights dbuf
    __shared__ float s_f[4096];                                   // f stash [cog][row][co32][col32]

    int tid = threadIdx.x, wv = tid >> 6, l = tid & 63, lg = l >> 4, ln = l & 15;
    int bid = blockIdx.x;
    int n = bid >> 5, strip = bid & 31, y0 = strip * 2;
    int cog = wv >> 2, rloc = wv & 3;          // convA wave = (co-half, local row)
    int grow = y0 - 1 + rloc;                  // convA output row
    bool rok = (unsigned)grow < 64u;

    // bias hoist
    float brz_[2][4], bf_[2][4];
    #pragma unroll
    for (int ct = 0; ct < 2; ++ct)
        #pragma unroll
        for (int r = 0; r < 4; ++r) {
            int co = cog * 32 + ct * 16 + lg * 4 + r;
            brz_[ct][r] = b_rz[co]; bf_[ct][r] = b_f[co];
        }

    // zero s_a edge columns (image cols -1, 64)
    if (!ZERO && tid < 64) {
        int r = tid >> 4, ce = (tid >> 3) & 1, g = tid & 7;
        int off = (r * 66 + (ce ? 65 : 0)) * 64 + g * 8;
        *(uint4*)&s_ah[off] = make_uint4(0, 0, 0, 0);
        *(uint4*)&s_al[off] = make_uint4(0, 0, 0, 0);
    }

    // ================= phase A: conv(prev_y, w_rz) =================
    f32x4 a1[2][4] = {}, a2[2][4] = {};
    uint2 wreg[3];
    if (!ZERO) {
        stage_y(ypk_prev, n, y0, 0, s_sth, s_stl, tid);
        wload16(wpkA, 0, tid, wreg);
        wwrite16(wreg, s_w[0], tid);
        wload16(wpkA, 1, tid, wreg);
        __syncthreads();

        int db = 0, fg = 0;
        #pragma unroll 1
        for (int chunk = 0; chunk < 4; ++chunk) {
            for (int ty = 0; ty < 3; ++ty, ++fg) {
                if (fg < 11) {
                    wwrite16(wreg, s_w[db ^ 1], tid);
                    if (fg + 2 < 12) wload16(wpkA, fg + 2, tid, wreg);
                }
                #pragma unroll
                for (int tx = 0; tx < 3; ++tx) {
                    half4v Ah[2], Al[2];
                    #pragma unroll
                    for (int ct = 0; ct < 2; ++ct) {
                        int co = cog * 32 + ct * 16 + ln;
                        int off = co * 20 + ((lg ^ (co & 3)) * 4);
                        Ah[ct] = *(const half4v*)&s_w[db][tx][0][off];
                        Al[ct] = *(const half4v*)&s_w[db][tx][1][off];
                    }
                    half4v Bh[4], Bl[4];
                    #pragma unroll
                    for (int st = 0; st < 4; ++st) {
                        int cc = st * 16 + ln + tx;
                        int off = ((rloc + ty) * 66 + cc) * 20 + ((lg ^ (cc & 3)) * 4);
                        Bh[st] = *(const half4v*)&s_sth[off];
                        Bl[st] = *(const half4v*)&s_stl[off];
                    }
                    #pragma unroll
                    for (int ct = 0; ct < 2; ++ct)
                        #pragma unroll
                        for (int st = 0; st < 4; ++st) {
                            a1[ct][st] = __builtin_amdgcn_mfma_f32_16x16x16f16(Ah[ct], Bh[st], a1[ct][st], 0, 0, 0);
                            a2[ct][st] = __builtin_amdgcn_mfma_f32_16x16x16f16(Ah[ct], Bl[st], a2[ct][st], 0, 0, 0);
                            a2[ct][st] = __builtin_amdgcn_mfma_f32_16x16x16f16(Al[ct], Bh[st], a2[ct][st], 0, 0, 0);
                        }
                }
                if (ty == 2 && chunk < 3) {
                    __syncthreads();
                    stage_y(ypk_prev, n, y0, chunk + 1, s_sth, s_stl, tid);
                }
                __syncthreads();
                db ^= 1;
            }
        }
    }

    // ---- phase A epilogue: f = sigmoid(conv + b + xi_i), a = py*f -> s_a ----
    wload16(wpkB, 0, tid, wreg);               // prefetch convB weights
    float freg[2][2][4];
    #pragma unroll
    for (int ct = 0; ct < 2; ++ct)
        #pragma unroll
        for (int st = 0; st < 4; ++st) {
            int col = st * 16 + ln;
            uint4 pyq = make_uint4(0, 0, 0, 0);
            if (!ZERO && rok)
                pyq = *(const uint4*)(ypk_prev + (((size_t)(n * 64 + grow) * 64 + col) * 64
                                                  + cog * 32 + ct * 16 + lg * 4));
            uint32_t pyu[4] = {pyq.x, pyq.y, pyq.z, pyq.w};
            unsigned short ah_[4], al_[4];
            #pragma unroll
            for (int r = 0; r < 4; ++r) {
                int co = cog * 32 + ct * 16 + lg * 4 + r;
                float conv = ZERO ? 0.0f : (a1[ct][st][r] + a2[ct][st][r] * (1.0f / 2048.0f));
                float xi = rok ? xt_t[(((size_t)n * 128 + co) * 64 + grow) * 64 + col] : 0.0f;
                float s = conv + brz_[ct][r] + xi;
                float fv = 1.0f / (1.0f + expf(-s));
                float py = h2f(pyu[r] >> 16) + h2f(pyu[r] & 0xFFFFu) * (1.0f / 2048.0f);
                float av = rok ? py * fv : 0.0f;
                split2(av, ah_[r], al_[r]);
                if (st < 2) freg[ct][st][r] = fv;
                else if (rloc == 1 || rloc == 2)
                    s_f[(((cog << 1) | (rloc >> 1)) * 32 + (ct * 16 + lg * 4 + r)) * 32
                        + (col - 32)] = fv;
            }
            if (!ZERO) {
                int cc = col + 1;
                int gco = cog * 4 + ct * 2 + (lg >> 1);
                int off = (rloc * 66 + cc) * 64 + ((gco ^ (cc & 7)) * 8) + (lg & 1) * 4;
                *(uint2*)&s_ah[off] = make_uint2((uint32_t)ah_[0] | ((uint32_t)ah_[1] << 16),
                                                 (uint32_t)ah_[2] | ((uint32_t)ah_[3] << 16));
                *(uint2*)&s_al[off] = make_uint2((uint32_t)al_[0] | ((uint32_t)al_[1] << 16),
                                                 (uint32_t)al_[2] | ((uint32_t)al_[3] << 16));
            }
        }
    wwrite16(wreg, s_w[0], tid);
    wload16(wpkB, 1, tid, wreg);
    __syncthreads();                           // s_a, s_f, convB w(g0) visible

    // ================= phase B: conv(a, w_f) from LDS =================
    int rowB = rloc >> 1;
    int colh = 1 - ((rloc ^ (rloc >> 1)) & 1); // rloc 1,2 -> 0 ; rloc 0,3 -> 1
    int colB0 = colh * 32;
    f32x4 b1[2][2] = {}, b2[2][2] = {};
    if (!ZERO) {
        int db = 0, fg = 0;
        #pragma unroll 1
        for (int chunk = 0; chunk < 4; ++chunk) {
            for (int ty = 0; ty < 3; ++ty, ++fg) {
                if (fg < 11) {
                    wwrite16(wreg, s_w[db ^ 1], tid);
                    if (fg + 2 < 12) wload16(wpkB, fg + 2, tid, wreg);
                }
                #pragma unroll
                for (int tx = 0; tx < 3; ++tx) {
                    half4v Ah[2], Al[2];
                    #pragma unroll
                    for (int ct = 0; ct < 2; ++ct) {
                        int co = cog * 32 + ct * 16 + ln;
                        int off = co * 20 + ((lg ^ (co & 3)) * 4);
                        Ah[ct] = *(const half4v*)&s_w[db][tx][0][off];
                        Al[ct] = *(const half4v*)&s_w[db][tx][1][off];
                    }
                    half4v Bh[2], Bl[2];
                    #pragma unroll
                    for (int st = 0; st < 2; ++st) {
                        int cc = colB0 + st * 16 + ln + tx;
                        int gB = chunk * 2 + (lg >> 1);
                        int off = ((rowB + ty) * 66 + cc) * 64 + ((gB ^ (cc & 7)) * 8)
                                + (lg & 1) * 4;
                        Bh[st] = *(const half4v*)&s_ah[off];
                        Bl[st] = *(const half4v*)&s_al[off];
                    }
                    #pragma unroll
                    for (int ct = 0; ct < 2; ++ct)
                        #pragma unroll
                        for (int st = 0; st < 2; ++st) {
                            b1[ct][st] = __builtin_amdgcn_mfma_f32_16x16x16f16(Ah[ct], Bh[st], b1[ct][st], 0, 0, 0);
                            b2[ct][st] = __builtin_amdgcn_mfma_f32_16x16x16f16(Ah[ct], Bl[st], b2[ct][st], 0, 0, 0);
                            b2[ct][st] = __builtin_amdgcn_mfma_f32_16x16x16f16(Al[ct], Bh[st], b2[ct][st], 0, 0, 0);
                        }
                }
                __syncthreads();
                db ^= 1;
            }
        }
    }

    // ---- phase B epilogue: GRU/spike update, outputs ----
    int grow2 = y0 + rowB;
    float thr_[2];
    #pragma unroll
    for (int st = 0; st < 2; ++st) {
        int col = colB0 + st * 16 + ln;
        thr_[st] = 1.0f / (1.0f + expf(-thr_rp[grow2 * 64 + col]));
    }
    #pragma unroll
    for (int ct = 0; ct < 2; ++ct)
        #pragma unroll
        for (int st = 0; st < 2; ++st) {
            int col = colB0 + st * 16 + ln;
            uint32_t pk[4];
            #pragma unroll
            for (int r = 0; r < 4; ++r) {
                int co = cog * 32 + ct * 16 + lg * 4 + r;
                size_t idx = (((size_t)n * 64 + co) * 64 + grow2) * 64 + col;
                float conv = ZERO ? 0.0f : (b1[ct][st][r] + b2[ct][st][r] * (1.0f / 2048.0f));
                float xi = xt_t[(((size_t)n * 128 + 64 + co) * 64 + grow2) * 64 + col];
                float s = conv + bf_[ct][r] + xi;
                float e2 = expf(2.0f * s);
                float g = 1.0f - 2.0f / (e2 + 1.0f);          // tanh(s)
                float fv = (colh == 0)
                    ? freg[ct][st][r]
                    : s_f[(((cog << 1) | rowB) * 32 + (ct * 16 + lg * 4 + r)) * 32
                          + (st * 16 + ln)];
                float hp = ZERO ? 0.0f : h_buf[idx];
                float hn = (1.0f - fv) * hp + fv * g;
                float d = hn - thr_[st];
                bool e = d > 0.0f;
                float y = e ? hn : 0.0f;
                ys[idx] = y;
                ev[idx] = e ? 1.0f : 0.0f;
                nd[idx] = (d < 0.0f) ? (thr_[st] - hn) : 0.0f;
                h_buf[idx] = e ? d : hn;                      // h - event*thr
                pk[r] = pack2(y);
            }
            *(uint4*)(ypk_out + (((size_t)(n * 64 + grow2) * 64 + col) * 64
                                 + cog * 32 + ct * 16 + lg * 4)) =
                make_uint4(pk[0], pk[1], pk[2], pk[3]);
        }
}

// ---------------------------------------------------------------------------
extern "C" void kernel_launch(void* const* d_in, const int* in_sizes, int n_in,
                              void* d_out, int out_size, void* d_ws, size_t ws_size,
                              hipStream_t stream) {
    (void)in_sizes; (void)n_in; (void)out_size; (void)ws_size;

    const float* xt     = (const float*)d_in[0];
    const float* w_rz   = (const float*)d_in[1];
    const float* b_rz   = (const float*)d_in[2];
    const float* w_f    = (const float*)d_in[3];
    const float* b_f    = (const float*)d_in[4];
    const float* thr_rp = (const float*)d_in[5];

    float* out = (float*)d_out;
    uint32_t* ypk0  = (uint32_t*)d_ws;          // ping (NCHW u32, 8 MB)
    uint32_t* ypk1  = ypk0 + NCHW;              // pong (8 MB)
    uint32_t* wpack = ypk1 + NCHW;              // 73728 u32
    float*    h_buf = (float*)(wpack + 73728);  // NCHW f32 (8 MB); total 24.3 MB

    float* ys0 = out;
    float* ev0 = out + (size_t)T_STEPS * NCHW;
    float* nd0 = ev0 + (size_t)T_STEPS * NCHW;

    prep_w<<<288, 256, 0, stream>>>(w_rz, w_f, wpack);
    const uint32_t* wpkA = wpack;
    const uint32_t* wpkB = wpack + 9 * 4 * 64 * 16;

    for (int t = 0; t < T_STEPS; ++t) {
        const float* xt_t = xt + (size_t)t * XTSTR;
        uint32_t* yprev = (t & 1) ? ypk1 : ypk0;
        uint32_t* ycur  = (t & 1) ? ypk0 : ypk1;
        float* ys_t = ys0 + (size_t)t * NCHW;
        float* ev_t = ev0 + (size_t)t * NCHW;
        float* nd_t = nd0 + (size_t)t * NCHW;
        if (t == 0)
            kStep<true><<<256, 512, 0, stream>>>(wpkA, wpkB, b_rz, b_f, xt_t, thr_rp,
                                                 yprev, ycur, h_buf, ys_t, ev_t, nd_t);
        else
            kStep<false><<<256, 512, 0, stream>>>(wpkA, wpkB, b_rz, b_f, xt_t, thr_rp,
                                                  yprev, ycur, h_buf, ys_t, ev_t, nd_t);
    }
}

// Round 6
// 792.313 us; speedup vs baseline: 2.0213x; 1.4811x over previous
//
#include <hip/hip_runtime.h>
#include <cstdint>

typedef _Float16 half8 __attribute__((ext_vector_type(8)));
typedef _Float16 half4 __attribute__((ext_vector_type(4)));
typedef float f32x4 __attribute__((ext_vector_type(4)));

#define T_STEPS 16
#define NB 8
#define CCH 64
#define HH 64
#define WW 64
#define HW 4096
#define NCHW (NB * CCH * HW)          // 2097152
#define XTSTR (NB * 2 * CCH * HW)

#define CI_PAD 40                      // halves per (r,c) cell: 80B stride, 16B aligned
#define IN_LDS (4 * 66 * CI_PAD)

__device__ __forceinline__ _Float16 u2h(unsigned short u) {
    union { unsigned short u; _Float16 h; } v; v.u = u; return v.h;
}
// fp32 -> f16 hi + f16 (residual*2048); recombine hi + lo/2048 ~ fp32-exact
__device__ __forceinline__ void split2h(float x, _Float16& hi, _Float16& lo) {
    hi = (_Float16)x;
    lo = (_Float16)((x - (float)hi) * 2048.0f);
}

// ---------------------------------------------------------------------------
// One-time weight prepack into split planes:
// layout [g][tap 9][chunk 2][ch 2][co 32][ci 32] halves (ci fastest)
// ---------------------------------------------------------------------------
__global__ __launch_bounds__(256) void prep_w(const float* __restrict__ w_rz,
                                              const float* __restrict__ w_f,
                                              _Float16* __restrict__ w_hi,
                                              _Float16* __restrict__ w_lo) {
    int i = blockIdx.x * 256 + threadIdx.x;
    if (i >= 2 * 9 * 2 * 2 * 32 * 32) return;
    int ci = i & 31, co = (i >> 5) & 31, ch = (i >> 10) & 1, chunk = (i >> 11) & 1;
    int gt = i >> 12; int tap = gt % 9; int g = gt / 9;
    const float* w = g ? w_f : w_rz;
    float v = w[(size_t)((ch * 32 + co) * CCH + (chunk * 32 + ci)) * 9 + tap];
    _Float16 hi, lo; split2h(v, hi, lo);
    w_hi[i] = hi; w_lo[i] = lo;
}

// ---------------------------------------------------------------------------
// Stage one 32-ci chunk of a split-plane image into LDS (pure 16B copies).
// Planes are [n][row][col][64 ci] f16. LDS cell stride CI_PAD=40 (80B).
// ---------------------------------------------------------------------------
__device__ __forceinline__ void stage_pl(const _Float16* __restrict__ ph,
                                         const _Float16* __restrict__ pl,
                                         int n, int y0, int chunk,
                                         _Float16* __restrict__ s_hi,
                                         _Float16* __restrict__ s_lo, int tid) {
    #pragma unroll
    for (int it = 0; it < 5; ++it) {
        int i = tid + it * 256;
        if (i >= 1056) break;                 // 4 rows x 66 cols x 4 granules
        int gg = i & 3; int tmp = i >> 2; int c = tmp % 66; int r = tmp / 66;
        int gr = y0 - 1 + r, gc = c - 1;
        uint4 uh = make_uint4(0, 0, 0, 0), ul = make_uint4(0, 0, 0, 0);
        if ((unsigned)gr < 64u && (unsigned)gc < 64u) {
            size_t base = (((size_t)n * 64 + gr) * 64 + gc) * 64 + chunk * 32 + gg * 8;
            uh = *(const uint4*)(ph + base);
            ul = *(const uint4*)(pl + base);
        }
        int off = (r * 66 + c) * CI_PAD + gg * 8;
        *(uint4*)&s_hi[off] = uh;
        *(uint4*)&s_lo[off] = ul;
    }
}

// ---------------------------------------------------------------------------
// Weight group (3 taps, one ci-chunk, one co-half): pure 8B copies.
// ---------------------------------------------------------------------------
__device__ __forceinline__ void wloadp(const _Float16* __restrict__ wh,
                                       const _Float16* __restrict__ wl,
                                       int fg, int ch, int tid, uint2* uh, uint2* ul) {
    int chunk = fg / 3, ty = fg - chunk * 3;
    #pragma unroll
    for (int tx = 0; tx < 3; ++tx) {
        size_t base = (size_t)(((ty * 3 + tx) * 2 + chunk) * 2 + ch) * 1024 + tid * 4;
        uh[tx] = *(const uint2*)(wh + base);
        ul[tx] = *(const uint2*)(wl + base);
    }
}
__device__ __forceinline__ void wwritep(const uint2* uh, const uint2* ul,
                                        _Float16 (*sw)[2][1024], int tid) {
    int co = tid >> 3, j = tid & 7;
    int pos = ((j >> 1) ^ (co ^ (co >> 2))) & 3;       // granule swizzle (verified r3)
    int off = co * 32 + pos * 8 + (j & 1) * 4;
    #pragma unroll
    for (int tx = 0; tx < 3; ++tx) {
        *(uint2*)&sw[tx][0][off] = uh[tx];
        *(uint2*)&sw[tx][1][off] = ul[tx];
    }
}

// ---------------------------------------------------------------------------
// Conv core: 32co x 128sp tile, K=32 split-f16 MFMA (verified round 3).
// ---------------------------------------------------------------------------
__device__ __forceinline__ void conv_core(const _Float16* __restrict__ in_h,
    const _Float16* __restrict__ in_l, const _Float16* __restrict__ wh,
    const _Float16* __restrict__ wl, int n, int y0, int ch, int tid,
    f32x4 acc1[2][2], f32x4 acc2[2][2],
    _Float16* s_in_h, _Float16* s_in_l, _Float16 (*s_w)[3][2][1024]) {

    int wv = tid >> 6, l = tid & 63, lg = l >> 4, ln = l & 15;
    int aoff = ln * 32 + ((lg ^ ln ^ (ln >> 2)) & 3) * 8;

    uint2 wrh[3], wrl[3];
    stage_pl(in_h, in_l, n, y0, 0, s_in_h, s_in_l, tid);
    wloadp(wh, wl, 0, ch, tid, wrh, wrl);
    wwritep(wrh, wrl, s_w[0], tid);
    wloadp(wh, wl, 1, ch, tid, wrh, wrl);
    __syncthreads();

    int db = 0;
    for (int gi = 0; gi < 6; ++gi) {
        int ty = gi % 3;
        if (gi < 5) {
            wwritep(wrh, wrl, s_w[db ^ 1], tid);
            if (gi + 2 < 6) wloadp(wh, wl, gi + 2, ch, tid, wrh, wrl);
        }
        #pragma unroll
        for (int tx = 0; tx < 3; ++tx) {
            half8 afh[2], afl[2];
            #pragma unroll
            for (int ct = 0; ct < 2; ++ct) {
                afh[ct] = *(const half8*)&s_w[db][tx][0][ct * 512 + aoff];
                afl[ct] = *(const half8*)&s_w[db][tx][1][ct * 512 + aoff];
            }
            half8 bfh[2], bfl[2];
            #pragma unroll
            for (int st = 0; st < 2; ++st) {
                int sp = wv * 32 + st * 16 + ln;
                int boff = (((sp >> 6) + ty) * 66 + (sp & 63) + tx) * CI_PAD + lg * 8;
                bfh[st] = *(const half8*)&s_in_h[boff];
                bfl[st] = *(const half8*)&s_in_l[boff];
            }
            #pragma unroll
            for (int ct = 0; ct < 2; ++ct)
                #pragma unroll
                for (int st = 0; st < 2; ++st) {
                    acc1[ct][st] = __builtin_amdgcn_mfma_f32_16x16x32_f16(afh[ct], bfh[st], acc1[ct][st], 0, 0, 0);
                    acc2[ct][st] = __builtin_amdgcn_mfma_f32_16x16x32_f16(afh[ct], bfl[st], acc2[ct][st], 0, 0, 0);
                    acc2[ct][st] = __builtin_amdgcn_mfma_f32_16x16x32_f16(afl[ct], bfh[st], acc2[ct][st], 0, 0, 0);
                }
        }
        if (gi == 2) {                       // chunk boundary: restage ci 32..63
            __syncthreads();
            stage_pl(in_h, in_l, n, y0, 1, s_in_h, s_in_l, tid);
        }
        __syncthreads();
        db ^= 1;
    }
}

// ---------------------------------------------------------------------------
// Kernel A: f = sigmoid(conv(prev_y, w_rz) + b_rz + xi_i); a = prev_y * f.
// ---------------------------------------------------------------------------
template<bool ZERO>
__global__ __launch_bounds__(256, 2) void kA(
    const _Float16* __restrict__ y_hi, const _Float16* __restrict__ y_lo,
    const _Float16* __restrict__ wh, const _Float16* __restrict__ wl,
    const float* __restrict__ b_rz, const float* __restrict__ xt_t,
    float* __restrict__ f_out,
    _Float16* __restrict__ a_hi, _Float16* __restrict__ a_lo) {

    __shared__ __align__(16) _Float16 s_in_h[IN_LDS];
    __shared__ __align__(16) _Float16 s_in_l[IN_LDS];
    __shared__ __align__(16) _Float16 s_w[2][3][2][1024];

    int tid = threadIdx.x, wv = tid >> 6, l = tid & 63, lg = l >> 4, ln = l & 15;
    // XCD swizzle: all 64 blocks of batch element n on one XCD
    int bid = ((blockIdx.x & 7) << 6) | (blockIdx.x >> 3);
    int n = bid >> 6, strip = (bid >> 1) & 31, ch = bid & 1, y0 = strip * 2;

    f32x4 acc1[2][2] = {}, acc2[2][2] = {};
    if (!ZERO)
        conv_core(y_hi, y_lo, wh, wl, n, y0, ch, tid, acc1, acc2, s_in_h, s_in_l, s_w);

    #pragma unroll
    for (int ct = 0; ct < 2; ++ct)
        #pragma unroll
        for (int st = 0; st < 2; ++st) {
            int sp = wv * 32 + st * 16 + ln, row = y0 + (sp >> 6), col = sp & 63;
            size_t pb = (((size_t)n * 64 + row) * 64 + col) * 64 + ch * 32 + ct * 16 + lg * 4;
            half4 pyh = {}, pyl = {};
            if (!ZERO) {
                pyh = *(const half4*)(y_hi + pb);
                pyl = *(const half4*)(y_lo + pb);
            }
            half4 avh, avl;
            #pragma unroll
            for (int r = 0; r < 4; ++r) {
                int co = ch * 32 + ct * 16 + lg * 4 + r;
                float conv = ZERO ? 0.0f
                    : (acc1[ct][st][r] + acc2[ct][st][r] * (1.0f / 2048.0f));
                int idx = ((n * CCH + co) * HH + row) * WW + col;
                float xi = xt_t[((n * 2 * CCH + co) * HH + row) * WW + col];
                float s = conv + b_rz[co] + xi;
                float f = 1.0f / (1.0f + expf(-s));
                f_out[idx] = f;
                float py = (float)pyh[r] + (float)pyl[r] * (1.0f / 2048.0f);
                float a = py * f;
                _Float16 hi, lo; split2h(a, hi, lo);
                avh[r] = hi; avl[r] = lo;
            }
            if (!ZERO) {
                *(half4*)(a_hi + pb) = avh;
                *(half4*)(a_lo + pb) = avl;
            }
        }
}

// ---------------------------------------------------------------------------
// Kernel B: g = tanh(conv(a, w_f) + b_f + xi_f); GRU/spike update; writes
// ys/ev/nd, h_buf, and split y planes for next step's kA.
// ---------------------------------------------------------------------------
template<bool ZERO>
__global__ __launch_bounds__(256, 2) void kB(
    const _Float16* __restrict__ a_hi, const _Float16* __restrict__ a_lo,
    const _Float16* __restrict__ wh, const _Float16* __restrict__ wl,
    const float* __restrict__ b_f, const float* __restrict__ xt_t,
    const float* __restrict__ f_in, const float* __restrict__ thr_rp,
    float* __restrict__ h_buf, float* __restrict__ ys,
    float* __restrict__ ev, float* __restrict__ nd,
    _Float16* __restrict__ y_hi, _Float16* __restrict__ y_lo) {

    __shared__ __align__(16) _Float16 s_in_h[IN_LDS];
    __shared__ __align__(16) _Float16 s_in_l[IN_LDS];
    __shared__ __align__(16) _Float16 s_w[2][3][2][1024];

    int tid = threadIdx.x, wv = tid >> 6, l = tid & 63, lg = l >> 4, ln = l & 15;
    int bid = ((blockIdx.x & 7) << 6) | (blockIdx.x >> 3);
    int n = bid >> 6, strip = (bid >> 1) & 31, ch = bid & 1, y0 = strip * 2;

    f32x4 acc1[2][2] = {}, acc2[2][2] = {};
    if (!ZERO)
        conv_core(a_hi, a_lo, wh, wl, n, y0, ch, tid, acc1, acc2, s_in_h, s_in_l, s_w);

    #pragma unroll
    for (int ct = 0; ct < 2; ++ct)
        #pragma unroll
        for (int st = 0; st < 2; ++st) {
            int sp = wv * 32 + st * 16 + ln, row = y0 + (sp >> 6), col = sp & 63;
            float thr = 1.0f / (1.0f + expf(-thr_rp[row * WW + col]));
            size_t pb = (((size_t)n * 64 + row) * 64 + col) * 64 + ch * 32 + ct * 16 + lg * 4;
            half4 yvh, yvl;
            #pragma unroll
            for (int r = 0; r < 4; ++r) {
                int co = ch * 32 + ct * 16 + lg * 4 + r;
                float conv = ZERO ? 0.0f
                    : (acc1[ct][st][r] + acc2[ct][st][r] * (1.0f / 2048.0f));
                int idx = ((n * CCH + co) * HH + row) * WW + col;
                float xi = xt_t[((n * 2 * CCH + CCH + co) * HH + row) * WW + col];
                float s  = conv + b_f[co] + xi;
                float e2 = expf(2.0f * s);
                float g  = 1.0f - 2.0f / (e2 + 1.0f);       // tanh(s)
                float f  = f_in[idx];
                float hp = ZERO ? 0.0f : h_buf[idx];
                float h  = (1.0f - f) * hp + f * g;
                float d  = h - thr;
                bool  e  = d > 0.0f;
                float y  = e ? h : 0.0f;
                ys[idx] = y;
                ev[idx] = e ? 1.0f : 0.0f;
                nd[idx] = (d < 0.0f) ? (thr - h) : 0.0f;
                h_buf[idx] = e ? d : h;                     // h - event*thr
                _Float16 hi, lo; split2h(y, hi, lo);
                yvh[r] = hi; yvl[r] = lo;
            }
            *(half4*)(y_hi + pb) = yvh;
            *(half4*)(y_lo + pb) = yvl;
        }
}

// ---------------------------------------------------------------------------
extern "C" void kernel_launch(void* const* d_in, const int* in_sizes, int n_in,
                              void* d_out, int out_size, void* d_ws, size_t ws_size,
                              hipStream_t stream) {
    (void)in_sizes; (void)n_in; (void)out_size; (void)ws_size;

    const float* xt     = (const float*)d_in[0];
    const float* w_rz   = (const float*)d_in[1];
    const float* b_rz   = (const float*)d_in[2];
    const float* w_f    = (const float*)d_in[3];
    const float* b_f    = (const float*)d_in[4];
    const float* thr_rp = (const float*)d_in[5];

    float* out = (float*)d_out;
    _Float16* y_hi = (_Float16*)d_ws;                 // 4 MB each plane
    _Float16* y_lo = y_hi + NCHW;
    _Float16* a_hi = y_lo + NCHW;
    _Float16* a_lo = a_hi + NCHW;
    float*    f_buf = (float*)(a_lo + NCHW);          // 8 MB
    float*    h_buf = f_buf + NCHW;                   // 8 MB
    _Float16* w_hi  = (_Float16*)(h_buf + NCHW);      // 73728 halves
    _Float16* w_lo  = w_hi + 73728;                   // total ~32.3 MB (= round 3)

    float* ys0 = out;
    float* ev0 = out + (size_t)T_STEPS * NCHW;
    float* nd0 = ev0 + (size_t)T_STEPS * NCHW;

    prep_w<<<288, 256, 0, stream>>>(w_rz, w_f, w_hi, w_lo);
    const _Float16* whA = w_hi,          * wlA = w_lo;
    const _Float16* whB = w_hi + 36864,  * wlB = w_lo + 36864;

    dim3 grid(512), block(256);
    for (int t = 0; t < T_STEPS; ++t) {
        const float* xt_t = xt + (size_t)t * XTSTR;
        float* ys_t = ys0 + (size_t)t * NCHW;
        float* ev_t = ev0 + (size_t)t * NCHW;
        float* nd_t = nd0 + (size_t)t * NCHW;
        if (t == 0) {
            kA<true><<<grid, block, 0, stream>>>(y_hi, y_lo, whA, wlA, b_rz, xt_t,
                                                 f_buf, a_hi, a_lo);
            kB<true><<<grid, block, 0, stream>>>(a_hi, a_lo, whB, wlB, b_f, xt_t,
                                                 f_buf, thr_rp, h_buf,
                                                 ys_t, ev_t, nd_t, y_hi, y_lo);
        } else {
            kA<false><<<grid, block, 0, stream>>>(y_hi, y_lo, whA, wlA, b_rz, xt_t,
                                                  f_buf, a_hi, a_lo);
            kB<false><<<grid, block, 0, stream>>>(a_hi, a_lo, whB, wlB, b_f, xt_t,
                                                  f_buf, thr_rp, h_buf,
                                                  ys_t, ev_t, nd_t, y_hi, y_lo);
        }
    }
}